// Round 2
// baseline (1047.867 us; speedup 1.0000x reference)
//
#include <hip/hip_runtime.h>
#include <math.h>

// ExpandFormerV15Complete — bucketed expert dispatch.
// Each token has at most ONE domain. out = h + 0.1*W2[d]^T gelu(W1[d]^T h).
//
// Kernel A (prep):  out[tok] = embed[x[tok]] for ALL tokens; build per-domain
//                   token lists in d_ws via block-aggregated atomics.
// Kernel B (expert): one block per 64-token tile of one domain. Stage W1[d]+W2[d]
//                   (64 KB) in LDS. lane = token; wave w computes hid slice
//                   [32w,32w+32) (weights are wave-uniform LDS broadcasts -> no
//                   conflicts, no shfl). 4 partial corr slices reduced via LDS
//                   (rotation swizzle breaks the stride-64-float bank pattern),
//                   then out += 0.1*corr (read-modify-write, out already = h).
//
// List order from atomics is non-deterministic, but each token's computation
// and output location depend only on the token itself -> output bits identical.

constexpr int BASE = 64;
constexpr int HIDD = 128;
constexpr int NDOM = 8;
constexpr int NTOK = 16 * 2048;
constexpr float CORR_SCALE = 0.1f;

// ---------------- Kernel A: base copy + domain bucketing ----------------
__global__ __launch_bounds__(512) void prep_kernel(
    const int*   __restrict__ x,
    const float* __restrict__ embed,
    const float* __restrict__ member,
    float*       __restrict__ out,
    int*         __restrict__ g_cnt,
    int*         __restrict__ list)
{
    __shared__ int lcnt[NDOM];
    __shared__ int gbase[NDOM];
    const int tid = threadIdx.x;
    if (tid < NDOM) lcnt[tid] = 0;
    __syncthreads();

    const int gt  = blockIdx.x * 512 + tid;   // 131072 threads = 32768 tok x 4 segs
    const int tok = gt >> 2;
    const int seg = gt & 3;
    const int id  = x[tok];

    // out = h (16 floats per thread, fully coalesced)
    const float4* e4 = (const float4*)embed;
    float4*       o4 = (float4*)out;
    #pragma unroll
    for (int k = 0; k < 4; ++k)
        o4[(size_t)tok * 16 + seg * 4 + k] = e4[(size_t)id * 16 + seg * 4 + k];

    int d = -1, rank = 0;
    if (seg == 0) {
        const float4 m0 = ((const float4*)member)[(size_t)id * 2];
        const float4 m1 = ((const float4*)member)[(size_t)id * 2 + 1];
        if      (m0.x > 0.5f) d = 0;
        else if (m0.y > 0.5f) d = 1;
        else if (m0.z > 0.5f) d = 2;
        else if (m0.w > 0.5f) d = 3;
        else if (m1.x > 0.5f) d = 4;
        else if (m1.y > 0.5f) d = 5;
        else if (m1.z > 0.5f) d = 6;
        else if (m1.w > 0.5f) d = 7;
        if (d >= 0) rank = atomicAdd(&lcnt[d], 1);
    }
    __syncthreads();
    if (tid < NDOM) gbase[tid] = lcnt[tid] ? atomicAdd(&g_cnt[tid], lcnt[tid]) : 0;
    __syncthreads();
    if (d >= 0) list[d * NTOK + gbase[d] + rank] = tok;
}

// ---------------- Kernel B: bucketed expert MLP ----------------
__global__ __launch_bounds__(256, 2) void expert_kernel(
    const int*   __restrict__ x,
    const float* __restrict__ embed,
    const float* __restrict__ W1,
    const float* __restrict__ W2,
    float*       __restrict__ out,
    const int*   __restrict__ g_cnt,
    const int*   __restrict__ list)
{
    __shared__ float ldsW[2 * BASE * HIDD];   // 64 KB: W1 | W2, reused for partials
    __shared__ int   s_cnt[NDOM];
    __shared__ int   s_tp[NDOM + 1];

    const int tid  = threadIdx.x;
    const int wave = tid >> 6;
    const int lane = tid & 63;

    if (tid == 0) {
        int acc = 0;
        for (int d = 0; d < NDOM; ++d) {
            const int c = g_cnt[d];
            s_cnt[d] = c;
            s_tp[d]  = acc;
            acc += (c + 63) >> 6;
        }
        s_tp[NDOM] = acc;
    }
    __syncthreads();
    const int total = s_tp[NDOM];

    for (int item = blockIdx.x; item < total; item += gridDim.x) {
        int d = 0;
        while (item >= s_tp[d + 1]) ++d;          // <=8 LDS reads, block-uniform
        const int tbase = (item - s_tp[d]) * 64;
        const int c_d   = s_cnt[d];

        __syncthreads();   // previous iteration's partial reads done before restage
        {
            const float4* w1g = (const float4*)(W1 + (size_t)d * BASE * HIDD);
            const float4* w2g = (const float4*)(W2 + (size_t)d * HIDD * BASE);
            float4* l4 = (float4*)ldsW;
            #pragma unroll
            for (int k = 0; k < 8; ++k) l4[tid + k * 256]        = w1g[tid + k * 256];
            #pragma unroll
            for (int k = 0; k < 8; ++k) l4[2048 + tid + k * 256] = w2g[tid + k * 256];
        }
        __syncthreads();

        const int  tix   = tbase + lane;
        const bool valid = tix < c_d;
        const int  t     = list[d * NTOK + (valid ? tix : tbase)];
        const int  id    = x[t];

        float h[BASE];
        {
            const float4* e4 = (const float4*)(embed + (size_t)id * BASE);
            #pragma unroll
            for (int k = 0; k < 16; ++k) {
                const float4 v = e4[k];
                h[4*k] = v.x; h[4*k+1] = v.y; h[4*k+2] = v.z; h[4*k+3] = v.w;
            }
        }

        float corr[BASE];
        #pragma unroll
        for (int c = 0; c < BASE; ++c) corr[c] = 0.0f;

        const int h0 = wave * 32;   // this wave's hid slice

        #pragma unroll
        for (int hc0 = 0; hc0 < 32; hc0 += 16) {
            float z[16];
            #pragma unroll
            for (int j = 0; j < 16; ++j) z[j] = 0.0f;

            #pragma unroll
            for (int c = 0; c < BASE; ++c) {
                const float  hcv = h[c];
                const float4* wr = (const float4*)&ldsW[c * HIDD + h0 + hc0];
                #pragma unroll
                for (int q = 0; q < 4; ++q) {
                    const float4 w = wr[q];     // wave-uniform -> LDS broadcast
                    z[4*q+0] = fmaf(hcv, w.x, z[4*q+0]);
                    z[4*q+1] = fmaf(hcv, w.y, z[4*q+1]);
                    z[4*q+2] = fmaf(hcv, w.z, z[4*q+2]);
                    z[4*q+3] = fmaf(hcv, w.w, z[4*q+3]);
                }
            }

            float g[16];
            #pragma unroll
            for (int j = 0; j < 16; ++j) {
                const float v = z[j];
                g[j] = 0.5f * v * (1.0f + erff(v * 0.70710678118654752f));  // exact GELU
            }

            #pragma unroll
            for (int j = 0; j < 16; ++j) {
                const float  gj = g[j];
                const float4* r4 = (const float4*)&ldsW[BASE * HIDD + (h0 + hc0 + j) * BASE];
                #pragma unroll
                for (int q = 0; q < 16; ++q) {
                    const float4 w = r4[q];     // wave-uniform broadcast
                    corr[4*q+0] = fmaf(gj, w.x, corr[4*q+0]);
                    corr[4*q+1] = fmaf(gj, w.y, corr[4*q+1]);
                    corr[4*q+2] = fmaf(gj, w.z, corr[4*q+2]);
                    corr[4*q+3] = fmaf(gj, w.w, corr[4*q+3]);
                }
            }
        }

        __syncthreads();   // weights no longer needed; reuse LDS for partials

        // partial corr write, rotation-swizzled: stored col = (j + 4*lane) & 63
        {
            float* part = ldsW + wave * 4096 + lane * 64;
            const int rot = (4 * lane) & 63;
            #pragma unroll
            for (int jq = 0; jq < 16; ++jq) {
                const int col = (4 * jq + rot) & 63;
                *(float4*)&part[col] =
                    make_float4(corr[4*jq], corr[4*jq+1], corr[4*jq+2], corr[4*jq+3]);
            }
        }
        __syncthreads();

        // reduce 4 wave-partials + RMW into out (out already holds h)
        #pragma unroll
        for (int rep = 0; rep < 4; ++rep) {
            const int it  = tid + rep * 256;
            const int tk  = it >> 4;
            const int q   = it & 15;
            const int col = (4 * q + 4 * tk) & 63;   // same rotation as writer lane tk
            const float4 s0 = *(const float4*)&ldsW[0 * 4096 + tk * 64 + col];
            const float4 s1 = *(const float4*)&ldsW[1 * 4096 + tk * 64 + col];
            const float4 s2 = *(const float4*)&ldsW[2 * 4096 + tk * 64 + col];
            const float4 s3 = *(const float4*)&ldsW[3 * 4096 + tk * 64 + col];
            const float sx = ((s0.x + s1.x) + s2.x) + s3.x;   // fixed order
            const float sy = ((s0.y + s1.y) + s2.y) + s3.y;
            const float sz = ((s0.z + s1.z) + s2.z) + s3.z;
            const float sw = ((s0.w + s1.w) + s2.w) + s3.w;
            if (tbase + tk < c_d) {
                const int t2 = list[d * NTOK + tbase + tk];
                float4* op = (float4*)(out + (size_t)t2 * BASE) + q;
                float4 o = *op;
                o.x = fmaf(CORR_SCALE, sx, o.x);
                o.y = fmaf(CORR_SCALE, sy, o.y);
                o.z = fmaf(CORR_SCALE, sz, o.z);
                o.w = fmaf(CORR_SCALE, sw, o.w);
                *op = o;
            }
        }
    }
}

// ---------------- fallback (round-1 kernel) if ws is too small ----------------
__global__ __launch_bounds__(256) void expand_mlp_fallback(
    const int* __restrict__ x, const float* __restrict__ embed,
    const float* __restrict__ W1, const float* __restrict__ W2,
    const float* __restrict__ member, float* __restrict__ out)
{
    const int lane = threadIdx.x & 63;
    const int wave = threadIdx.x >> 6;
    const int tok  = blockIdx.x * 4 + wave;
    if (tok >= NTOK) return;
    const int id = x[tok];
    const float hval = embed[(size_t)id * BASE + lane];
    const float m = (lane < NDOM) ? member[(size_t)id * NDOM + lane] : 0.0f;
    const unsigned long long bal = __ballot(m > 0.5f);
    float result = hval;
    if (bal) {
        const int d = (int)__builtin_ctzll(bal);
        const float2* w1p = (const float2*)(W1 + (size_t)d * BASE * HIDD);
        float z0 = 0.0f, z1 = 0.0f;
        #pragma unroll 16
        for (int c = 0; c < BASE; ++c) {
            const float  hc = __shfl(hval, c);
            const float2 w  = w1p[c * (HIDD / 2) + lane];
            z0 = fmaf(hc, w.x, z0);
            z1 = fmaf(hc, w.y, z1);
        }
        const float k = 0.70710678118654752f;
        const float g0 = 0.5f * z0 * (1.0f + erff(z0 * k));
        const float g1 = 0.5f * z1 * (1.0f + erff(z1 * k));
        const float* w2p = W2 + (size_t)d * HIDD * BASE;
        float acc = 0.0f;
        #pragma unroll 16
        for (int h2 = 0; h2 < HIDD / 2; ++h2) {
            const float a = __shfl(g0, h2);
            const float b = __shfl(g1, h2);
            acc = fmaf(a, w2p[(size_t)(2 * h2)     * BASE + lane], acc);
            acc = fmaf(b, w2p[(size_t)(2 * h2 + 1) * BASE + lane], acc);
        }
        result = fmaf(CORR_SCALE, acc, hval);
    }
    out[(size_t)tok * BASE + lane] = result;
}

extern "C" void kernel_launch(void* const* d_in, const int* in_sizes, int n_in,
                              void* d_out, int out_size, void* d_ws, size_t ws_size,
                              hipStream_t stream) {
    const int*   x      = (const int*)  d_in[0];
    const float* embed  = (const float*)d_in[1];
    const float* W1     = (const float*)d_in[2];
    const float* W2     = (const float*)d_in[3];
    const float* member = (const float*)d_in[4];
    float*       out    = (float*)d_out;

    const size_t need = 256 + (size_t)NDOM * NTOK * sizeof(int);
    if (ws_size < need) {
        hipLaunchKernelGGL(expand_mlp_fallback, dim3(NTOK / 4), dim3(256), 0, stream,
                           x, embed, W1, W2, member, out);
        return;
    }

    int* g_cnt = (int*)d_ws;
    int* list  = (int*)((char*)d_ws + 256);

    hipMemsetAsync(d_ws, 0, 32, stream);   // zero the 8 domain counters
    hipLaunchKernelGGL(prep_kernel, dim3(NTOK * 4 / 512), dim3(512), 0, stream,
                       x, embed, member, out, g_cnt, list);
    hipLaunchKernelGGL(expert_kernel, dim3(512), dim3(256), 0, stream,
                       x, embed, W1, W2, out, g_cnt, list);
}

// Round 3
// 74.053 us; speedup vs baseline: 14.1502x; 14.1502x over previous
//
#include <hip/hip_runtime.h>
#include <math.h>

// ExpandFormerV15Complete — bucketed experts, R1-style per-wave mapping.
// out = h + 0.1 * W2[d]^T gelu(W1[d]^T h), each token in at most one domain.
//
// prep:   out[tok] = embed[x[tok]] for ALL tokens; bucket active tokens into
//         per-domain lists (block-aggregated atomics). (unchanged from R2 — fast)
// expert: item = (domain d, 16-token tile). Block stages W1[d]+W2[d] (64 KB)
//         in LDS; each of 4 waves handles 4 tokens SEQUENTIALLY with the
//         R1 mapping (lane = output index, h broadcast by shfl). Per-thread
//         state ~12 floats -> no spills (R2's failure mode).
//         LDS reads are 2-way bank aliased only (free per m136).

constexpr int BASE = 64;
constexpr int HIDD = 128;
constexpr int NDOM = 8;
constexpr int NTOK = 16 * 2048;
constexpr float CORR_SCALE = 0.1f;
constexpr int TILE = 16;          // tokens per work item
constexpr int TPW  = TILE / 4;    // tokens per wave (4)

__device__ __forceinline__ float gelu_exact(float v) {
    return 0.5f * v * (1.0f + erff(v * 0.70710678118654752f));
}

// ---------------- Kernel A: base copy + domain bucketing (unchanged) ----------------
__global__ __launch_bounds__(512) void prep_kernel(
    const int*   __restrict__ x,
    const float* __restrict__ embed,
    const float* __restrict__ member,
    float*       __restrict__ out,
    int*         __restrict__ g_cnt,
    int*         __restrict__ list)
{
    __shared__ int lcnt[NDOM];
    __shared__ int gbase[NDOM];
    const int tid = threadIdx.x;
    if (tid < NDOM) lcnt[tid] = 0;
    __syncthreads();

    const int gt  = blockIdx.x * 512 + tid;   // 131072 threads = 32768 tok x 4 segs
    const int tok = gt >> 2;
    const int seg = gt & 3;
    const int id  = x[tok];

    const float4* e4 = (const float4*)embed;
    float4*       o4 = (float4*)out;
    #pragma unroll
    for (int k = 0; k < 4; ++k)
        o4[(size_t)tok * 16 + seg * 4 + k] = e4[(size_t)id * 16 + seg * 4 + k];

    int d = -1, rank = 0;
    if (seg == 0) {
        const float4 m0 = ((const float4*)member)[(size_t)id * 2];
        const float4 m1 = ((const float4*)member)[(size_t)id * 2 + 1];
        if      (m0.x > 0.5f) d = 0;
        else if (m0.y > 0.5f) d = 1;
        else if (m0.z > 0.5f) d = 2;
        else if (m0.w > 0.5f) d = 3;
        else if (m1.x > 0.5f) d = 4;
        else if (m1.y > 0.5f) d = 5;
        else if (m1.z > 0.5f) d = 6;
        else if (m1.w > 0.5f) d = 7;
        if (d >= 0) rank = atomicAdd(&lcnt[d], 1);
    }
    __syncthreads();
    if (tid < NDOM) gbase[tid] = lcnt[tid] ? atomicAdd(&g_cnt[tid], lcnt[tid]) : 0;
    __syncthreads();
    if (d >= 0) list[d * NTOK + gbase[d] + rank] = tok;
}

// ---------------- Kernel B: bucketed expert, per-wave token processing ----------------
__global__ __launch_bounds__(256) void expert_kernel(
    const int*   __restrict__ x,
    const float* __restrict__ embed,
    const float* __restrict__ W1,
    const float* __restrict__ W2,
    float*       __restrict__ out,
    const int*   __restrict__ g_cnt,
    const int*   __restrict__ list)
{
    __shared__ float lW[2 * BASE * HIDD];   // W1 (8192 floats) | W2 (8192 floats)
    __shared__ int   s_cnt[NDOM];
    __shared__ int   s_tp[NDOM + 1];

    const int tid  = threadIdx.x;
    const int wave = tid >> 6;
    const int lane = tid & 63;

    if (tid == 0) {
        int acc = 0;
        for (int d = 0; d < NDOM; ++d) {
            const int c = g_cnt[d];
            s_cnt[d] = c;
            s_tp[d]  = acc;
            acc += (c + TILE - 1) / TILE;
        }
        s_tp[NDOM] = acc;
    }
    __syncthreads();
    const int total = s_tp[NDOM];

    int last_d = -1;
    for (int item = blockIdx.x; item < total; item += gridDim.x) {
        int d = 0;
        while (item >= s_tp[d + 1]) ++d;           // block-uniform
        const int tbase = (item - s_tp[d]) * TILE;
        const int c_d   = s_cnt[d];

        if (d != last_d) {                          // block-uniform branch
            __syncthreads();                        // prior pass done with lW
            const float4* w1g = (const float4*)(W1 + (size_t)d * BASE * HIDD);
            const float4* w2g = (const float4*)(W2 + (size_t)d * HIDD * BASE);
            float4* l4 = (float4*)lW;
            #pragma unroll
            for (int k = 0; k < 8; ++k) l4[tid + k * 256]        = w1g[tid + k * 256];
            #pragma unroll
            for (int k = 0; k < 8; ++k) l4[2048 + tid + k * 256] = w2g[tid + k * 256];
            __syncthreads();
            last_d = d;
        }

        const int t0 = tbase + wave * TPW;
        int tn = c_d - t0;
        tn = tn < 0 ? 0 : (tn > TPW ? TPW : tn);   // wave-uniform token count
        if (tn == 0) continue;

        const int* __restrict__ lp = list + (size_t)d * NTOK;
        const float* __restrict__ lW2 = lW + BASE * HIDD;

        // prefetch all of this wave's token ids + h rows (constant indices only)
        int   tk[TPW];
        int   idk[TPW];
        float hk[TPW];
        #pragma unroll
        for (int k = 0; k < TPW; ++k) {
            const int tix = t0 + k;
            tk[k] = lp[tix < c_d ? tix : (c_d - 1)];
        }
        #pragma unroll
        for (int k = 0; k < TPW; ++k) idk[k] = x[tk[k]];
        #pragma unroll
        for (int k = 0; k < TPW; ++k)
            hk[k] = embed[(size_t)idk[k] * BASE + lane];

        #pragma unroll
        for (int k = 0; k < TPW; ++k) {
            if (k < tn) {
                const float hval = hk[k];

                // ---- mv1: z[lane] and z[lane+64]; W1 from LDS, h by shfl broadcast
                float z0 = 0.0f, z1 = 0.0f;
                #pragma unroll
                for (int c = 0; c < BASE; ++c) {
                    const float hc = __shfl(hval, c);
                    z0 = fmaf(hc, lW[c * HIDD + lane],      z0);
                    z1 = fmaf(hc, lW[c * HIDD + 64 + lane], z1);
                }

                const float g0 = gelu_exact(z0);   // hid j = lane
                const float g1 = gelu_exact(z1);   // hid j = lane + 64

                // ---- mv2: corr[lane] = sum_j g_j * W2[j][lane]
                float acc0 = 0.0f, acc1 = 0.0f;
                #pragma unroll
                for (int jq = 0; jq < 32; ++jq) {
                    const float a = __shfl(g0, 2 * jq);
                    const float b = __shfl(g0, 2 * jq + 1);
                    acc0 = fmaf(a, lW2[(2 * jq)     * BASE + lane], acc0);
                    acc1 = fmaf(b, lW2[(2 * jq + 1) * BASE + lane], acc1);
                }
                #pragma unroll
                for (int jq = 0; jq < 32; ++jq) {
                    const float a = __shfl(g1, 2 * jq);
                    const float b = __shfl(g1, 2 * jq + 1);
                    acc0 = fmaf(a, lW2[(64 + 2 * jq)     * BASE + lane], acc0);
                    acc1 = fmaf(b, lW2[(64 + 2 * jq + 1) * BASE + lane], acc1);
                }

                // overwrite: prep wrote h here; hval is bit-identical to it
                out[(size_t)tk[k] * BASE + lane] =
                    fmaf(CORR_SCALE, acc0 + acc1, hval);
            }
        }
    }
}

// ---------------- fallback (round-1 kernel) if ws is too small ----------------
__global__ __launch_bounds__(256) void expand_mlp_fallback(
    const int* __restrict__ x, const float* __restrict__ embed,
    const float* __restrict__ W1, const float* __restrict__ W2,
    const float* __restrict__ member, float* __restrict__ out)
{
    const int lane = threadIdx.x & 63;
    const int wave = threadIdx.x >> 6;
    const int tok  = blockIdx.x * 4 + wave;
    if (tok >= NTOK) return;
    const int id = x[tok];
    const float hval = embed[(size_t)id * BASE + lane];
    const float m = (lane < NDOM) ? member[(size_t)id * NDOM + lane] : 0.0f;
    const unsigned long long bal = __ballot(m > 0.5f);
    float result = hval;
    if (bal) {
        const int d = (int)__builtin_ctzll(bal);
        const float2* w1p = (const float2*)(W1 + (size_t)d * BASE * HIDD);
        float z0 = 0.0f, z1 = 0.0f;
        #pragma unroll 16
        for (int c = 0; c < BASE; ++c) {
            const float  hc = __shfl(hval, c);
            const float2 w  = w1p[c * (HIDD / 2) + lane];
            z0 = fmaf(hc, w.x, z0);
            z1 = fmaf(hc, w.y, z1);
        }
        const float g0 = gelu_exact(z0);
        const float g1 = gelu_exact(z1);
        const float* w2p = W2 + (size_t)d * HIDD * BASE;
        float acc = 0.0f;
        #pragma unroll 16
        for (int h2 = 0; h2 < HIDD / 2; ++h2) {
            const float a = __shfl(g0, h2);
            const float b = __shfl(g1, h2);
            acc = fmaf(a, w2p[(size_t)(2 * h2)     * BASE + lane], acc);
            acc = fmaf(b, w2p[(size_t)(2 * h2 + 1) * BASE + lane], acc);
        }
        result = fmaf(CORR_SCALE, acc, hval);
    }
    out[(size_t)tok * BASE + lane] = result;
}

extern "C" void kernel_launch(void* const* d_in, const int* in_sizes, int n_in,
                              void* d_out, int out_size, void* d_ws, size_t ws_size,
                              hipStream_t stream) {
    const int*   x      = (const int*)  d_in[0];
    const float* embed  = (const float*)d_in[1];
    const float* W1     = (const float*)d_in[2];
    const float* W2     = (const float*)d_in[3];
    const float* member = (const float*)d_in[4];
    float*       out    = (float*)d_out;

    const size_t need = 256 + (size_t)NDOM * NTOK * sizeof(int);
    if (ws_size < need) {
        hipLaunchKernelGGL(expand_mlp_fallback, dim3(NTOK / 4), dim3(256), 0, stream,
                           x, embed, W1, W2, member, out);
        return;
    }

    int* g_cnt = (int*)d_ws;
    int* list  = (int*)((char*)d_ws + 256);

    hipMemsetAsync(d_ws, 0, 32, stream);   // zero the 8 domain counters
    hipLaunchKernelGGL(prep_kernel, dim3(NTOK * 4 / 512), dim3(512), 0, stream,
                       x, embed, member, out, g_cnt, list);
    hipLaunchKernelGGL(expert_kernel, dim3(512), dim3(256), 0, stream,
                       x, embed, W1, W2, out, g_cnt, list);
}

// Round 4
// 25.965 us; speedup vs baseline: 40.3574x; 2.8521x over previous
//
#include <hip/hip_runtime.h>
#include <math.h>

// ExpandFormerV15Complete — bucketed experts via bf16 MFMA (swapped operands).
// out = h + 0.1 * W2[d]^T gelu(W1[d]^T h), each token in at most one domain.
//
// prep:   bucket active tokens into per-domain lists; out = h for INACTIVE
//         tokens only (expert fully writes active rows).
// expert: item = (domain d, 64-token tile); block = 4 waves, wave = 16 tokens.
//         Swapped GEMMs: Z^T = A(W1^T)·B(H^T), corr^T = A(W2^T)·B(P^T) with
//         v_mfma_f32_16x16x32_bf16. Weights staged ONCE per domain in LDS in
//         fragment order (one ds_read_b128 per A-frag). H^T B-frags gathered
//         from embed directly into registers. GELU output round-trips through
//         a per-wave XOR-swizzled LDS tile (ds_write_b64 / ds_read_b128).
//         Epilogue: out[tok] = h(fp32, re-read L1-hot) + 0.1*corr (no RMW).
//
// Fragment layouts (16x16x32 bf16):
//   A: lane l, reg i -> A[l%16][8*(l/16)+i]      (+16*mt rows, +32*kk k)
//   B: lane l, reg i -> B[8*(l/16)+i][l%16]
//   D: lane l, reg r -> D[4*(l/16)+r][l%16]      (verified, m89)

typedef __attribute__((ext_vector_type(8))) short short8;
typedef __attribute__((ext_vector_type(4))) float f32x4;

constexpr int BASE = 64;
constexpr int HIDD = 128;
constexpr int NDOM = 8;
constexpr int NTOK = 16 * 2048;
constexpr float CORR_SCALE = 0.1f;

__device__ __forceinline__ ushort f2bf(float f) {           // RNE f32->bf16
    uint u = __float_as_uint(f);
    return (ushort)((u + 0x7FFFu + ((u >> 16) & 1u)) >> 16);
}
__device__ __forceinline__ uint pack2(float a, float b) {
    return (uint)f2bf(a) | ((uint)f2bf(b) << 16);
}
__device__ __forceinline__ float gelu_exact(float v) {
    return 0.5f * v * (1.0f + erff(v * 0.70710678118654752f));
}

// ---------------- Kernel A: bucketing + inactive-token copy ----------------
__global__ __launch_bounds__(512) void prep_kernel(
    const int*   __restrict__ x,
    const float* __restrict__ embed,
    const float* __restrict__ member,
    float*       __restrict__ out,
    int*         __restrict__ g_cnt,
    int*         __restrict__ list)
{
    __shared__ int lcnt[NDOM];
    __shared__ int gbase[NDOM];
    const int tid = threadIdx.x;
    if (tid < NDOM) lcnt[tid] = 0;
    __syncthreads();

    const int gt  = blockIdx.x * 512 + tid;   // 131072 = 32768 tok x 4 segs
    const int tok = gt >> 2;
    const int seg = gt & 3;
    const int id  = x[tok];

    const float4 m0 = ((const float4*)member)[(size_t)id * 2];
    const float4 m1 = ((const float4*)member)[(size_t)id * 2 + 1];
    const float  s  = m0.x + m0.y + m0.z + m0.w + m1.x + m1.y + m1.z + m1.w;
    const float  df = m0.y + 2.f*m0.z + 3.f*m0.w + 4.f*m1.x + 5.f*m1.y + 6.f*m1.z + 7.f*m1.w;
    const bool   act = s > 0.5f;
    const int    d   = (int)(df + 0.5f);      // exact: one-hot floats

    int rank = 0;
    if (act && seg == 0) rank = atomicAdd(&lcnt[d], 1);

    if (!act) {   // expert writes active rows fully; copy only inactive here
        const float4* e4 = (const float4*)embed;
        float4*       o4 = (float4*)out;
        #pragma unroll
        for (int k = 0; k < 4; ++k)
            o4[(size_t)tok * 16 + seg * 4 + k] = e4[(size_t)id * 16 + seg * 4 + k];
    }
    __syncthreads();
    if (tid < NDOM) gbase[tid] = lcnt[tid] ? atomicAdd(&g_cnt[tid], lcnt[tid]) : 0;
    __syncthreads();
    if (act && seg == 0) list[d * NTOK + gbase[d] + rank] = tok;
}

// ---------------- Kernel B: MFMA expert ----------------
__global__ __launch_bounds__(256) void expert_kernel(
    const int*   __restrict__ x,
    const float* __restrict__ embed,
    const float* __restrict__ W1,
    const float* __restrict__ W2,
    float*       __restrict__ out,
    const int*   __restrict__ g_cnt,
    const int*   __restrict__ list)
{
    __shared__ short8 lW1f[16 * 64];   // W1^T frag-ordered: frag(mt*2+kk), lane
    __shared__ short8 lW2f[16 * 64];   // W2^T frag-ordered: frag(mt*4+kk), lane
    __shared__ short8 lPf[4][256];     // per-wave P tile [16 tok][128 hid] bf16, swizzled
    __shared__ int s_cnt[NDOM];
    __shared__ int s_tp[NDOM + 1];

    const int tid  = threadIdx.x;
    const int wv   = tid >> 6;
    const int lane = tid & 63;
    const int g    = lane >> 4;        // k-group within fragment
    const int tk16 = lane & 15;        // token slot within wave's 16

    if (tid == 0) {
        int acc = 0;
        for (int d = 0; d < NDOM; ++d) {
            const int c = g_cnt[d];
            s_cnt[d] = c;
            s_tp[d]  = acc;
            acc += (c + 63) >> 6;
        }
        s_tp[NDOM] = acc;
    }
    __syncthreads();
    const int total = s_tp[NDOM];

    const float4* e4 = (const float4*)embed;
    int last_d = -1;

    for (int item = blockIdx.x; item < total; item += gridDim.x) {
        int d = 0;
        while (item >= s_tp[d + 1]) ++d;            // block-uniform
        const int tbase = (item - s_tp[d]) * 64;
        const int c_d   = s_cnt[d];

        if (d != last_d) {                           // block-uniform branch
            __syncthreads();                         // prior item done with lW*
            ushort* w1e = (ushort*)lW1f;
            ushort* w2e = (ushort*)lW2f;
            const float4* W1g = (const float4*)(W1 + (size_t)d * BASE * HIDD);
            const float4* W2g = (const float4*)(W2 + (size_t)d * HIDD * BASE);
            // W1[c][j] (64x128): unit = (c-pair, j-quad). value -> frag(mt=j/16, kk=c/32),
            // lane = 16*((c>>3)&3) + j%16, reg i = c&7 (pair c,c+1 -> consecutive i).
            #pragma unroll
            for (int r = 0; r < 4; ++r) {
                const int u  = tid + r * 256;
                const int cp = u >> 5, jq = u & 31;
                const float4 a = W1g[(2 * cp) * 32 + jq];
                const float4 b = W1g[(2 * cp + 1) * 32 + jq];
                const int c  = 2 * cp;
                const int kk = c >> 5, gg = (c >> 3) & 3, i = c & 7;
                const float av[4] = {a.x, a.y, a.z, a.w};
                const float bv[4] = {b.x, b.y, b.z, b.w};
                #pragma unroll
                for (int q = 0; q < 4; ++q) {
                    const int j  = 4 * jq + q;
                    const int mt = j >> 4, ls = gg * 16 + (j & 15);
                    *(uint*)&w1e[((mt * 2 + kk) * 64 + ls) * 8 + i] = pack2(av[q], bv[q]);
                }
            }
            // W2[j][c] (128x64): unit = (j-pair, c-quad). value -> frag(mt=c/16, kk=j/32),
            // lane = 16*((j>>3)&3) + c%16, reg i = j&7.
            #pragma unroll
            for (int r = 0; r < 4; ++r) {
                const int u  = tid + r * 256;
                const int jp = u >> 4, cq = u & 15;
                const float4 a = W2g[(2 * jp) * 16 + cq];
                const float4 b = W2g[(2 * jp + 1) * 16 + cq];
                const int j2 = 2 * jp;
                const int kk = j2 >> 5, gg = (j2 >> 3) & 3, i = j2 & 7;
                const float av[4] = {a.x, a.y, a.z, a.w};
                const float bv[4] = {b.x, b.y, b.z, b.w};
                #pragma unroll
                for (int q = 0; q < 4; ++q) {
                    const int c2 = 4 * cq + q;
                    const int mt = c2 >> 4, ls = gg * 16 + (c2 & 15);
                    *(uint*)&w2e[((mt * 4 + kk) * 64 + ls) * 8 + i] = pack2(av[q], bv[q]);
                }
            }
            __syncthreads();
            last_d = d;
        }

        // ---- this wave's token (one per 16-lane slot; all 4 g-groups same token)
        const int  tix   = tbase + wv * 16 + tk16;
        const bool valid = tix < c_d;
        const int  t     = list[(size_t)d * NTOK + (valid ? tix : (c_d - 1))];
        const int  id    = x[t];

        // ---- gather B-frags of H^T: lane needs h[token tk16][32*kk + 8*g + 0..7]
        short8 bh[2];
        #pragma unroll
        for (int kk = 0; kk < 2; ++kk) {
            const float4 v0 = e4[(size_t)id * 16 + kk * 8 + g * 2];
            const float4 v1 = e4[(size_t)id * 16 + kk * 8 + g * 2 + 1];
            short8 sv;
            sv[0] = (short)f2bf(v0.x); sv[1] = (short)f2bf(v0.y);
            sv[2] = (short)f2bf(v0.z); sv[3] = (short)f2bf(v0.w);
            sv[4] = (short)f2bf(v1.x); sv[5] = (short)f2bf(v1.y);
            sv[6] = (short)f2bf(v1.z); sv[7] = (short)f2bf(v1.w);
            bh[kk] = sv;
        }

        // ---- GEMM1: Z^T[j][tok], M=128 (8 mt), K=64 (2 kk)
        f32x4 acc1[8];
        #pragma unroll
        for (int mt = 0; mt < 8; ++mt) acc1[mt] = (f32x4){0.f, 0.f, 0.f, 0.f};
        #pragma unroll
        for (int kk = 0; kk < 2; ++kk) {
            #pragma unroll
            for (int mt = 0; mt < 8; ++mt) {
                const short8 a = lW1f[(mt * 2 + kk) * 64 + lane];
                acc1[mt] = __builtin_amdgcn_mfma_f32_16x16x32_bf16(a, bh[kk], acc1[mt], 0, 0, 0);
            }
        }

        // ---- GELU + pack to P[tok][j] bf16 in LDS (XOR-swizzled rows)
        char* Pb = (char*)&lPf[wv][0];
        const int swz = (tk16 & 7) << 4;
        #pragma unroll
        for (int mt = 0; mt < 8; ++mt) {
            const float g0 = gelu_exact(acc1[mt][0]);   // j = 16mt + 4g + reg
            const float g1 = gelu_exact(acc1[mt][1]);
            const float g2 = gelu_exact(acc1[mt][2]);
            const float g3 = gelu_exact(acc1[mt][3]);
            uint2 pw;
            pw.x = pack2(g0, g1);
            pw.y = pack2(g2, g3);
            *(uint2*)(Pb + tk16 * 256 + ((mt * 32 + g * 8) ^ swz)) = pw;
        }

        // ---- GEMM2: corr^T[c][tok], M=64 (4 mt), K=128 (4 kk); B = P^T from LDS
        f32x4 acc2[4];
        #pragma unroll
        for (int mt = 0; mt < 4; ++mt) acc2[mt] = (f32x4){0.f, 0.f, 0.f, 0.f};
        #pragma unroll
        for (int kk = 0; kk < 4; ++kk) {
            const short8 b2 = *(const short8*)(Pb + tk16 * 256 + ((kk * 64 + g * 16) ^ swz));
            #pragma unroll
            for (int mt = 0; mt < 4; ++mt) {
                const short8 a = lW2f[(mt * 4 + kk) * 64 + lane];
                acc2[mt] = __builtin_amdgcn_mfma_f32_16x16x32_bf16(a, b2, acc2[mt], 0, 0, 0);
            }
        }

        // ---- epilogue: out[t][c] = h[c] + 0.1*corr[c]; lane covers c = 16mt+4g+{0..3}
        if (valid) {
            float4* o4 = (float4*)out;
            #pragma unroll
            for (int mt = 0; mt < 4; ++mt) {
                const int q4 = 4 * mt + g;                 // float4 index = (16mt+4g)/4
                const float4 h4 = e4[(size_t)id * 16 + q4];
                float4 rv;
                rv.x = fmaf(CORR_SCALE, acc2[mt][0], h4.x);
                rv.y = fmaf(CORR_SCALE, acc2[mt][1], h4.y);
                rv.z = fmaf(CORR_SCALE, acc2[mt][2], h4.z);
                rv.w = fmaf(CORR_SCALE, acc2[mt][3], h4.w);
                o4[(size_t)t * 16 + q4] = rv;
            }
        }
    }
}

// ---------------- fallback (round-1 kernel) if ws is too small ----------------
__global__ __launch_bounds__(256) void expand_mlp_fallback(
    const int* __restrict__ x, const float* __restrict__ embed,
    const float* __restrict__ W1, const float* __restrict__ W2,
    const float* __restrict__ member, float* __restrict__ out)
{
    const int lane = threadIdx.x & 63;
    const int wave = threadIdx.x >> 6;
    const int tok  = blockIdx.x * 4 + wave;
    if (tok >= NTOK) return;
    const int id = x[tok];
    const float hval = embed[(size_t)id * BASE + lane];
    const float m = (lane < NDOM) ? member[(size_t)id * NDOM + lane] : 0.0f;
    const unsigned long long bal = __ballot(m > 0.5f);
    float result = hval;
    if (bal) {
        const int d = (int)__builtin_ctzll(bal);
        const float2* w1p = (const float2*)(W1 + (size_t)d * BASE * HIDD);
        float z0 = 0.0f, z1 = 0.0f;
        #pragma unroll 16
        for (int c = 0; c < BASE; ++c) {
            const float  hc = __shfl(hval, c);
            const float2 w  = w1p[c * (HIDD / 2) + lane];
            z0 = fmaf(hc, w.x, z0);
            z1 = fmaf(hc, w.y, z1);
        }
        const float g0 = gelu_exact(z0);
        const float g1 = gelu_exact(z1);
        const float* w2p = W2 + (size_t)d * HIDD * BASE;
        float acc = 0.0f;
        #pragma unroll 16
        for (int h2 = 0; h2 < HIDD / 2; ++h2) {
            const float a = __shfl(g0, h2);
            const float b = __shfl(g1, h2);
            acc = fmaf(a, w2p[(size_t)(2 * h2)     * BASE + lane], acc);
            acc = fmaf(b, w2p[(size_t)(2 * h2 + 1) * BASE + lane], acc);
        }
        result = fmaf(CORR_SCALE, acc, hval);
    }
    out[(size_t)tok * BASE + lane] = result;
}

extern "C" void kernel_launch(void* const* d_in, const int* in_sizes, int n_in,
                              void* d_out, int out_size, void* d_ws, size_t ws_size,
                              hipStream_t stream) {
    const int*   x      = (const int*)  d_in[0];
    const float* embed  = (const float*)d_in[1];
    const float* W1     = (const float*)d_in[2];
    const float* W2     = (const float*)d_in[3];
    const float* member = (const float*)d_in[4];
    float*       out    = (float*)d_out;

    const size_t need = 256 + (size_t)NDOM * NTOK * sizeof(int);
    if (ws_size < need) {
        hipLaunchKernelGGL(expand_mlp_fallback, dim3(NTOK / 4), dim3(256), 0, stream,
                           x, embed, W1, W2, member, out);
        return;
    }

    int* g_cnt = (int*)d_ws;
    int* list  = (int*)((char*)d_ws + 256);

    hipMemsetAsync(d_ws, 0, 32, stream);   // zero the 8 domain counters
    hipLaunchKernelGGL(prep_kernel, dim3(NTOK * 4 / 512), dim3(512), 0, stream,
                       x, embed, member, out, g_cnt, list);
    hipLaunchKernelGGL(expert_kernel, dim3(512), dim3(256), 0, stream,
                       x, embed, W1, W2, out, g_cnt, list);
}